// Round 7
// baseline (482.904 us; speedup 1.0000x reference)
//
#include <hip/hip_runtime.h>
#include <stdint.h>

// ---------------- problem constants ----------------
#define S_LEN 2048
#define HID   2048
#define NHEAD 16
#define HD    128     // head dim
#define NQK   8192    // concat q,k rows of [w_q; w_k]
#define K_HID 2048

typedef _Float16 f16x8 __attribute__((ext_vector_type(8)));
typedef float    f32x4 __attribute__((ext_vector_type(4)));

__device__ __forceinline__ unsigned short f2h(float f) {
    _Float16 h = (_Float16)f;                    // RNE
    union { _Float16 h; unsigned short u; } c; c.h = h;
    return c.u;
}
__device__ __forceinline__ float h2f(unsigned short b) {
    union { unsigned short u; _Float16 h; } c; c.u = b;
    return (float)c.h;
}
__device__ __forceinline__ float softplus_f(float x) {
    return (x > 20.f) ? x : log1pf(expf(x));
}
// 2 f32 -> packed 2xfp16 (RTZ) in one v_cvt_pkrtz
__device__ __forceinline__ unsigned pk2h(float a, float b) {
    auto w = __builtin_amdgcn_cvt_pkrtz(a, b);
    union { decltype(w) h; unsigned u; } c; c.h = w;
    return c.u;
}
#define EXP2F(x) __builtin_amdgcn_exp2f(x)
#define LOG2E 1.44269504088896f
#define LN2F  0.6931471805599453f
// async global->LDS, 16 B/lane; LDS dest = wave-uniform base + lane*16
__device__ __forceinline__ void gload_lds16(const unsigned short* g, unsigned short* l) {
    __builtin_amdgcn_global_load_lds(
        (const __attribute__((address_space(1))) unsigned int*)g,
        (__attribute__((address_space(3))) unsigned int*)l, 16, 0, 0);
}
// raw barrier (no vmcnt drain) + compiler memory fences
__device__ __forceinline__ void bar() {
    asm volatile("" ::: "memory");
    __builtin_amdgcn_s_barrier();
    asm volatile("" ::: "memory");
}
#define VMCNT(n) asm volatile("s_waitcnt vmcnt(" #n ")" ::: "memory")

// ---------------- fused cast fp32 -> fp16, 5 segments ----------------
__global__ __launch_bounds__(256) void cast5(const float* __restrict__ hs,
                                             const float* __restrict__ wq,
                                             const float* __restrict__ wk,
                                             const float* __restrict__ wv,
                                             const float* __restrict__ wo,
                                             unsigned short* __restrict__ hs16,
                                             unsigned short* __restrict__ wqk16,
                                             unsigned short* __restrict__ wv16,
                                             unsigned short* __restrict__ wo16) {
    int b = blockIdx.x;
    const float* src;
    unsigned short* dst;
    int i;
    if (b < 4096)       { src = hs; dst = hs16;                          i = b; }
    else if (b < 12288) { src = wq; dst = wqk16;                         i = b - 4096; }
    else if (b < 20480) { src = wk; dst = wqk16 + (size_t)4096 * K_HID;  i = b - 12288; }
    else if (b < 24576) { src = wv; dst = wv16;                          i = b - 20480; }
    else                { src = wo; dst = wo16;                          i = b - 24576; }
    int idx = i * 256 + threadIdx.x;
    float4 v = ((const float4*)src)[idx];
    ushort4 o;
    o.x = f2h(v.x); o.y = f2h(v.y); o.z = f2h(v.z); o.w = f2h(v.w);
    ((ushort4*)dst)[idx] = o;
}

// ---------------- shared NT-GEMM body (fp16 in, fp16 or fp32 out) ----------
// 128x128 tile, BK=32, 4 waves (2x2), 4x4 MFMA tiles/wave; m97 staging.
template <bool OUT_F16>
__device__ __forceinline__ void gemm_body(const unsigned short* __restrict__ A,
                                          const unsigned short* __restrict__ B,
                                          void* __restrict__ Cv,
                                          int m0, int n0, int N,
                                          unsigned short* As, unsigned short* Bs) {
    const int t    = threadIdx.x;
    const int wave = t >> 6;
    const int lane = t & 63;
    const int wm   = wave >> 1, wn = wave & 1;
    const int lrow = lane & 15, quad = lane >> 4;
    const int srow = lane >> 2;
    const int scol = (lane & 3) * 8;

    f32x4 acc[4][4];
    for (int i = 0; i < 4; ++i)
        for (int j = 0; j < 4; ++j)
            acc[i][j] = (f32x4){0.f, 0.f, 0.f, 0.f};

    for (int k0 = 0; k0 < K_HID; k0 += 32) {
        for (int c = 0; c < 2; ++c) {
            int ch = wave * 2 + c;     // 0..7
            int row = ch * 16 + srow;  // 0..127
            gload_lds16(A + (size_t)(m0 + row) * K_HID + k0 + scol, &As[ch * 512]);
            gload_lds16(B + (size_t)(n0 + row) * K_HID + k0 + scol, &Bs[ch * 512]);
        }
        __syncthreads();

        f16x8 af[4], bfr[4];
        for (int tm = 0; tm < 4; ++tm)
            af[tm]  = *(const f16x8*)(&As[(wm * 64 + tm * 16 + lrow) * 32 + quad * 8]);
        for (int tn = 0; tn < 4; ++tn)
            bfr[tn] = *(const f16x8*)(&Bs[(wn * 64 + tn * 16 + lrow) * 32 + quad * 8]);
        for (int tm = 0; tm < 4; ++tm)
            for (int tn = 0; tn < 4; ++tn)
                acc[tm][tn] = __builtin_amdgcn_mfma_f32_16x16x32_f16(af[tm], bfr[tn], acc[tm][tn], 0, 0, 0);
        __syncthreads();
    }

    for (int tm = 0; tm < 4; ++tm)
        for (int tn = 0; tn < 4; ++tn) {
            int col = n0 + wn * 64 + tn * 16 + lrow;
            for (int r = 0; r < 4; ++r) {
                int row = m0 + wm * 64 + tm * 16 + quad * 4 + r;
                if (OUT_F16)
                    ((unsigned short*)Cv)[(size_t)row * N + col] = f2h(acc[tm][tn][r]);
                else
                    ((float*)Cv)[(size_t)row * N + col] = acc[tm][tn][r];
            }
        }
}

// legacy fused launch (fallback only): QK projection + V^T projection
__global__ __launch_bounds__(256) void gemm_qkv(const unsigned short* __restrict__ hs16,
                                                const unsigned short* __restrict__ wqk16,
                                                const unsigned short* __restrict__ wv16,
                                                unsigned short* __restrict__ qk16,
                                                unsigned short* __restrict__ Vt) {
    __shared__ __align__(16) unsigned short As[128 * 32];
    __shared__ __align__(16) unsigned short Bs[128 * 32];
    int b = blockIdx.x;
    if (b < 1024) {
        gemm_body<true>(hs16, wqk16, qk16, (b >> 6) * 128, (b & 63) * 128, NQK, As, Bs);
    } else {
        b -= 1024;
        gemm_body<true>(wv16, hs16, Vt, (b >> 4) * 128, (b & 15) * 128, S_LEN, As, Bs);
    }
}

// plain single GEMM (128^2 tile; used for V^T and O-projection)
template <bool OUT_F16>
__global__ __launch_bounds__(256) void gemm_nt_f16(const unsigned short* __restrict__ A,
                                                   const unsigned short* __restrict__ B,
                                                   void* __restrict__ Cv,
                                                   int M, int N, int Kd) {
    __shared__ __align__(16) unsigned short As[128 * 32];
    __shared__ __align__(16) unsigned short Bs[128 * 32];
    gemm_body<OUT_F16>(A, B, Cv, blockIdx.y * 128, blockIdx.x * 128, N, As, Bs);
}

// ---------------- 256x256 cross-phase GEMM + FUSED prep epilogue -----------
// Main loop unchanged (zigzag quadrant walk, counted vmcnt, 4 bars/tile).
// LAUNCH BOUNDS (512, 1): the 128 KiB dynamic LDS already caps residency at
// 1 block/CU (2 waves/SIMD), so the old (512,2) 256-reg/wave clamp bought no
// occupancy and forced the fused epilogue (acc AGPR->VGPR reads + Lf/cos/sin
// temporaries) to SPILL into the main loop: ~4 KB scratch/thread = 550 MB of
// HBM writes/dispatch (R5/R6 signature). (512,1) -> 512 regs/wave, no spill.
__global__ __launch_bounds__(512, 1) void gemm256_qk(const unsigned short* __restrict__ A,
                                                     const unsigned short* __restrict__ B,
                                                     const float* __restrict__ cosb,
                                                     const float* __restrict__ sinb,
                                                     unsigned short* __restrict__ Qo,
                                                     unsigned short* __restrict__ Ko,
                                                     float* __restrict__ kb_out) {
    extern __shared__ __align__(16) unsigned short lds[];   // 65536 halves
    __shared__ float sred[3][256];                           // lg2 x2, ksq
    const int t    = threadIdx.x;
    const int wave = t >> 6;
    const int lane = t & 63;
    const int wm   = wave >> 2, wn = wave & 3;     // 2 x 4 wave grid
    const int lrow = lane & 15, quad = lane >> 4;

    const int x  = blockIdx.x & 7;
    const int sl = blockIdx.x >> 3;                // 0..31
    const int tm = ((x >> 2) << 2) + (sl >> 3);    // 0..7
    const int tn = ((x & 3) << 3) + (sl & 7);      // 0..31
    const int m0 = tm << 8, n0 = tn << 8;

    const int srow = lane >> 2;                               // row in subtile
    const int scol = ((lane & 3) * 8) ^ ((lane >> 5) << 4);   // halves
    const unsigned short* Ag = A + (size_t)(m0 + wave * 16 + srow) * K_HID + scol;
    const unsigned short* Bg = B + (size_t)(n0 + wave * 16 + srow) * K_HID + scol;

    const int swz = (lrow * 32 + quad * 8) ^ ((lrow >> 3) << 4);

    f32x4 acc[8][4];
    #pragma unroll
    for (int i = 0; i < 8; ++i)
        #pragma unroll
        for (int j = 0; j < 4; ++j) acc[i][j] = (f32x4){0.f, 0.f, 0.f, 0.f};

    {
        unsigned short* la = lds + wave * 1024;
        gload_lds16(Ag,               la);
        gload_lds16(Ag + 32,          la + 512);
        gload_lds16(Ag + 262144,      la + 8192);
        gload_lds16(Ag + 262144 + 32, la + 8704);
        unsigned short* lb = la + 16384;
        gload_lds16(Bg,               lb);
        gload_lds16(Bg + 32,          lb + 512);
        gload_lds16(Bg + 262144,      lb + 8192);
        gload_lds16(Bg + 262144 + 32, lb + 8704);
    }
    VMCNT(0);
    bar();   // tile 0 published

    f16x8 ah[4][2], b01[2][2];

    const int NT = K_HID / 64;   // 32
    #pragma unroll 1
    for (int t2 = 0; t2 < NT; ++t2) {
        const int buf = t2 & 1;
        const unsigned short* Lb = lds + buf * 32768;
        unsigned short*       Ln = lds + (buf ^ 1) * 32768 + wave * 1024;
        const int k1  = (t2 + 1) * 64;
        const bool pre = (t2 < NT - 1);

        f16x8 al[4][2], b23[2][2];

        // ---- S0: stage A(t+1) | read al(t) | MFMA Q(1,0) of t-1 | read b01(t) ----
        if (pre) {
            gload_lds16(Ag + k1,               Ln);
            gload_lds16(Ag + k1 + 32,          Ln + 512);
            gload_lds16(Ag + 262144 + k1,      Ln + 8192);
            gload_lds16(Ag + 262144 + k1 + 32, Ln + 8704);
        }
        #pragma unroll
        for (int i = 0; i < 4; ++i) {
            al[i][0] = *(const f16x8*)(Lb + (wm * 8 + i) * 1024 + swz);
            al[i][1] = *(const f16x8*)(Lb + (wm * 8 + i) * 1024 + 512 + swz);
        }
        if (t2) {
            __builtin_amdgcn_s_setprio(1);
            #pragma unroll
            for (int i = 0; i < 4; ++i)
                #pragma unroll
                for (int j = 0; j < 2; ++j) {
                    acc[4 + i][j] = __builtin_amdgcn_mfma_f32_16x16x32_f16(ah[i][0], b01[j][0], acc[4 + i][j], 0, 0, 0);
                    acc[4 + i][j] = __builtin_amdgcn_mfma_f32_16x16x32_f16(ah[i][1], b01[j][1], acc[4 + i][j], 0, 0, 0);
                }
            __builtin_amdgcn_s_setprio(0);
        }
        #pragma unroll
        for (int j = 0; j < 2; ++j) {
            b01[j][0] = *(const f16x8*)(Lb + 16384 + (wn * 4 + j) * 1024 + swz);
            b01[j][1] = *(const f16x8*)(Lb + 16384 + (wn * 4 + j) * 1024 + 512 + swz);
        }
        bar();

        // ---- S1: stage B(t+1) | read b23(t) || MFMA Q(0,0) = al*b01 ----
        if (pre) {
            gload_lds16(Bg + k1,               Ln + 16384);
            gload_lds16(Bg + k1 + 32,          Ln + 16896);
            gload_lds16(Bg + 262144 + k1,      Ln + 24576);
            gload_lds16(Bg + 262144 + k1 + 32, Ln + 25088);
        }
        #pragma unroll
        for (int j = 0; j < 2; ++j) {
            b23[j][0] = *(const f16x8*)(Lb + 16384 + (wn * 4 + 2 + j) * 1024 + swz);
            b23[j][1] = *(const f16x8*)(Lb + 16384 + (wn * 4 + 2 + j) * 1024 + 512 + swz);
        }
        __builtin_amdgcn_s_setprio(1);
        #pragma unroll
        for (int i = 0; i < 4; ++i)
            #pragma unroll
            for (int j = 0; j < 2; ++j) {
                acc[i][j] = __builtin_amdgcn_mfma_f32_16x16x32_f16(al[i][0], b01[j][0], acc[i][j], 0, 0, 0);
                acc[i][j] = __builtin_amdgcn_mfma_f32_16x16x32_f16(al[i][1], b01[j][1], acc[i][j], 0, 0, 0);
            }
        __builtin_amdgcn_s_setprio(0);
        bar();

        // ---- S2: read ah(t) || MFMA Q(0,1) = al*b23 ----
        #pragma unroll
        for (int i = 0; i < 4; ++i) {
            ah[i][0] = *(const f16x8*)(Lb + (wm * 8 + 4 + i) * 1024 + swz);
            ah[i][1] = *(const f16x8*)(Lb + (wm * 8 + 4 + i) * 1024 + 512 + swz);
        }
        __builtin_amdgcn_s_setprio(1);
        #pragma unroll
        for (int i = 0; i < 4; ++i)
            #pragma unroll
            for (int j = 0; j < 2; ++j) {
                acc[i][2 + j] = __builtin_amdgcn_mfma_f32_16x16x32_f16(al[i][0], b23[j][0], acc[i][2 + j], 0, 0, 0);
                acc[i][2 + j] = __builtin_amdgcn_mfma_f32_16x16x32_f16(al[i][1], b23[j][1], acc[i][2 + j], 0, 0, 0);
            }
        __builtin_amdgcn_s_setprio(0);
        bar();

        // ---- S3: MFMA Q(1,1) = ah*b23 ; publish tile t+1 ----
        __builtin_amdgcn_s_setprio(1);
        #pragma unroll
        for (int i = 0; i < 4; ++i)
            #pragma unroll
            for (int j = 0; j < 2; ++j) {
                acc[4 + i][2 + j] = __builtin_amdgcn_mfma_f32_16x16x32_f16(ah[i][0], b23[j][0], acc[4 + i][2 + j], 0, 0, 0);
                acc[4 + i][2 + j] = __builtin_amdgcn_mfma_f32_16x16x32_f16(ah[i][1], b23[j][1], acc[4 + i][2 + j], 0, 0, 0);
            }
        __builtin_amdgcn_s_setprio(0);
        VMCNT(0);
        bar();
    }

    // deferred final quadrant Q(1,0) of the last tile
    __builtin_amdgcn_s_setprio(1);
    #pragma unroll
    for (int i = 0; i < 4; ++i)
        #pragma unroll
        for (int j = 0; j < 2; ++j) {
            acc[4 + i][j] = __builtin_amdgcn_mfma_f32_16x16x32_f16(ah[i][0], b01[j][0], acc[4 + i][j], 0, 0, 0);
            acc[4 + i][j] = __builtin_amdgcn_mfma_f32_16x16x32_f16(ah[i][1], b01[j][1], acc[4 + i][j], 0, 0, 0);
        }
    __builtin_amdgcn_s_setprio(0);
    bar();   // every wave's LDS reads consumed -> LDS free for epilogue reuse

    // ================= fused prep epilogue =================
    const int  headq = tn & 15;
    const bool isK   = (tn >= 16);
    float* Lf = (float*)lds;                  // 256 x 128 f32 exchange
    unsigned short* Ls = lds;                 // ushort view (fp16 staging)
    const int swl = (quad & 1) << 4;          // == ((row>>2)&1)<<4 for this lane's rows

    // E1: sigma waves (wn>=2): inv = rsqrt(softplus+eps) -> Lf; lg2 row partials
    if (wn >= 2) {
        #pragma unroll
        for (int m = 0; m < 8; ++m)
            #pragma unroll
            for (int r = 0; r < 4; ++r) {
                const int row = wm * 128 + m * 16 + quad * 4 + r;
                float lgs = 0.f;
                #pragma unroll
                for (int n = 0; n < 4; ++n) {
                    const int d = (wn - 2) * 64 + n * 16 + lrow;
                    float xv = acc[m][n][r];
                    float sp = (xv > 20.f) ? xv
                             : LN2F * __log2f(1.f + EXP2F(xv * LOG2E));
                    float sg = sp + 1e-4f;
                    Lf[row * 128 + (d ^ swl)] = rsqrtf(sg);
                    if (isK) lgs += __log2f(sg);
                }
                if (isK) {
                    lgs += __shfl_xor(lgs, 1); lgs += __shfl_xor(lgs, 2);
                    lgs += __shfl_xor(lgs, 4); lgs += __shfl_xor(lgs, 8);
                    if (lrow == 0) sred[wn - 2][row] = lgs;
                }
            }
    }
    bar();   // inv published

    // E2: mu waves: w = acc*inv in-place; publish the half the partner needs
    if (wn < 2) {
        #pragma unroll
        for (int m = 0; m < 8; ++m)
            #pragma unroll
            for (int n = 0; n < 4; ++n) {
                const int d = wn * 64 + n * 16 + lrow;
                #pragma unroll
                for (int r = 0; r < 4; ++r) {
                    const int row = wm * 128 + m * 16 + quad * 4 + r;
                    float w = acc[m][n][r] * Lf[row * 128 + (d ^ swl)];
                    acc[m][n][r] = w;
                    const bool keep = (wn == 0) ? (m < 4) : (m >= 4);
                    if (!keep) Lf[row * 128 + (d ^ swl)] = w;   // own slot, 1:1
                }
            }
    }
    bar();   // cross-half w published; "keep" slots (stale inv) now DEAD

    // E3: RoPE pairs -> fp16 staged into the dead checkerboard of Lf.
    // Dead slots: rows rr<64 at d<64 (fb=0), rows rr>=64 at d>=64 (fb=64)
    // -> 256 B per row = exactly 128 fp16. Disjoint from live w-slots read here.
    if (wn < 2) {
        const int mlo = (wn == 0) ? 0 : 4;
        #pragma unroll
        for (int mi = 0; mi < 4; ++mi) {
            const int m = mlo + mi;
            #pragma unroll
            for (int r = 0; r < 4; ++r) {
                const int row = wm * 128 + m * 16 + quad * 4 + r;
                const int rr  = row & 127;
                const int fb  = (rr < 64) ? 0 : 64;
                const int s   = m0 + row;
                unsigned short* st = Ls + (row * 128 + fb) * 2;
                float kq = 0.f;
                #pragma unroll
                for (int n = 0; n < 4; ++n) {
                    const int dl = n * 16 + lrow;              // low-half index
                    float c  = cosb[(size_t)s * HD + dl];
                    float sn = sinb[(size_t)s * HD + dl];
                    float wlo, whi;
                    if (wn == 0) { wlo = acc[m][n][r]; whi = Lf[row * 128 + ((dl + 64) ^ swl)]; }
                    else         { whi = acc[m][n][r]; wlo = Lf[row * 128 + (dl ^ swl)]; }
                    float olo = wlo * c - whi * sn;
                    float ohi = whi * c + wlo * sn;
                    if (!isK) {
                        st[dl]      = f2h(olo * LOG2E);
                        st[dl + 64] = f2h(ohi * LOG2E);
                    } else {
                        unsigned short klo = f2h(olo), khi = f2h(ohi);
                        st[dl]      = klo;
                        st[dl + 64] = khi;
                        float a = h2f(klo), b2 = h2f(khi);
                        kq += a * a + b2 * b2;
                    }
                }
                if (isK) {
                    kq += __shfl_xor(kq, 1); kq += __shfl_xor(kq, 2);
                    kq += __shfl_xor(kq, 4); kq += __shfl_xor(kq, 8);
                    if (lrow == 0) sred[2][row] = kq;
                }
            }
        }
    }
    bar();   // staging + sred complete

    // copy-out: block output = contiguous 64 KB; uint4 per lane, wave-contiguous
    {
        unsigned short* Go = (isK ? Ko : Qo) + ((size_t)headq * S_LEN + m0) * HD;
        #pragma unroll
        for (int pass = 0; pass < 8; ++pass) {
            int idx = pass * 4096 + t * 8;       // halves
            int row = idx >> 7;
            int d   = idx & 127;
            int rr  = row & 127;
            int fb  = (rr < 64) ? 0 : 64;
            uint4 v = *(const uint4*)(Ls + (row * 128 + fb) * 2 + d);
            *(uint4*)(Go + idx) = v;
        }
        if (isK && t < 256) {
            const int row = t;
            kb_out[(size_t)headq * S_LEN + m0 + row] =
                -0.5f * (LOG2E * sred[2][row] + sred[0][row] + sred[1][row]);
        }
    }
}

// ---------------- prep (FALLBACK PATH ONLY) --------------------------------
__global__ __launch_bounds__(256) void prep_qk(const unsigned short* __restrict__ qk,
                                               const float* __restrict__ cosb,
                                               const float* __restrict__ sinb,
                                               unsigned short* __restrict__ Q16,
                                               unsigned short* __restrict__ K16,
                                               float* __restrict__ kbias) {
    int gid  = blockIdx.x * 4 + (threadIdx.x >> 6);
    int lane = threadIdx.x & 63;
    int h = gid >> 11;
    int s = gid & 2047;
    int d1 = lane, d2 = lane + 64;
    const unsigned short* row = qk + (size_t)s * NQK;
    float c1 = cosb[s * HD + d1], c2 = cosb[s * HD + d2];
    float s1 = sinb[s * HD + d1], s2 = sinb[s * HD + d2];
    size_t ob = ((size_t)h * S_LEN + s) * HD;

    {   // Q side (scaled by log2e)
        int base = h * 256;
        float mu1 = h2f(row[base + d1]),       mu2 = h2f(row[base + d2]);
        float sg1 = softplus_f(h2f(row[base + 128 + d1])) + 1e-4f;
        float sg2 = softplus_f(h2f(row[base + 128 + d2])) + 1e-4f;
        float w1 = mu1 * rsqrtf(sg1), w2 = mu2 * rsqrtf(sg2);
        float o1 = w1 * c1 - w2 * s1;
        float o2 = w2 * c2 + w1 * s2;
        Q16[ob + d1] = f2h(o1 * LOG2E);
        Q16[ob + d2] = f2h(o2 * LOG2E);
    }
    {   // K side + bias from ROUNDED k̂
        int base = 4096 + h * 256;
        float mu1 = h2f(row[base + d1]),       mu2 = h2f(row[base + d2]);
        float sg1 = softplus_f(h2f(row[base + 128 + d1])) + 1e-4f;
        float sg2 = softplus_f(h2f(row[base + 128 + d2])) + 1e-4f;
        float w1 = mu1 * rsqrtf(sg1), w2 = mu2 * rsqrtf(sg2);
        float o1 = w1 * c1 - w2 * s1;
        float o2 = w2 * c2 + w1 * s2;
        unsigned short k1 = f2h(o1), k2 = f2h(o2);
        K16[ob + d1] = k1; K16[ob + d2] = k2;
        float r1 = h2f(k1), r2 = h2f(k2);
        float part = r1 * r1 + r2 * r2 + logf(sg1) + logf(sg2);
        for (int off = 32; off > 0; off >>= 1) part += __shfl_down(part, off);
        if (lane == 0) kbias[(size_t)h * S_LEN + s] = -0.5f * LOG2E * part;
    }
}

// ---------------- flash attention, fp16 MFMA, key-split partials -----------
// (unchanged from R4: swapped QK^T, exp2 domain, XCD-remapped flat grid)
__global__ __launch_bounds__(256, 2) void flash_mfma(const unsigned short* __restrict__ Q16,
                                                     const unsigned short* __restrict__ K16,
                                                     const unsigned short* __restrict__ Vt,
                                                     const float* __restrict__ kbias,
                                                     unsigned short* __restrict__ OP,
                                                     float* __restrict__ ML) {
    constexpr int LV = 72;   // P row pad
    __shared__ __align__(16) unsigned short Khs[4 * 64 * 32];    // 16 KB
    __shared__ __align__(16) unsigned short Vts[2 * 128 * 32];   // 16 KB
    __shared__ __align__(16) unsigned short Ps[128 * LV];        // 18.4 KB
    __shared__ float kb[64];

    const int t    = threadIdx.x;
    const int bb   = blockIdx.x;
    const int cc   = (bb & 7) | (((bb >> 7) & 3) << 3);   // combo 0..31
    const int h    = cc & 15;
    const int kz   = cc >> 4;
    const int q0   = ((bb >> 3) & 15) * 128;
    const int wave = t >> 6;
    const int lane = t & 63;
    const int lrow = lane & 15, quad = lane >> 4;
    const int srow = lane >> 2;
    const int scol = (lane & 3) * 8;

    f16x8 qf[2][4];
    for (int m = 0; m < 2; ++m) {
        size_t rb = ((size_t)h * S_LEN + q0 + wave * 32 + m * 16 + lrow) * HD;
        for (int kk = 0; kk < 4; ++kk)
            qf[m][kk] = *(const f16x8*)(Q16 + rb + kk * 32 + quad * 8);
    }

    float mrow[2], lsum[2];
    f32x4 Ofr[2][8];
    for (int m = 0; m < 2; ++m) { mrow[m] = -INFINITY; lsum[m] = 0.f; }
    for (int m = 0; m < 2; ++m)
        for (int d = 0; d < 8; ++d) Ofr[m][d] = (f32x4){0.f, 0.f, 0.f, 0.f};

    const int kbeg = kz * 1024;
    for (int k0 = kbeg; k0 < kbeg + 1024; k0 += 64) {
        {
            const unsigned short* kgb = K16 + ((size_t)h * S_LEN + k0) * HD;
            const unsigned short* vgb = Vt + ((size_t)h * HD) * S_LEN + k0;
            for (int c = 0; c < 4; ++c) {
                int ch = wave * 4 + c;                 // 0..15
                int kk = ch >> 2;
                int r  = (ch & 3) * 16 + srow;
                gload_lds16(kgb + (size_t)r * HD + kk * 32 + scol, &Khs[ch * 512]);
                int kc = ch >> 3;
                int r2 = (ch & 7) * 16 + srow;
                gload_lds16(vgb + (size_t)r2 * S_LEN + kc * 32 + scol, &Vts[ch * 512]);
            }
            if (t < 64) kb[t] = kbias[(size_t)h * S_LEN + k0 + t];
        }
        __syncthreads();

        f32x4 sc[2][4];
        for (int m = 0; m < 2; ++m)
            for (int nt = 0; nt < 4; ++nt) sc[m][nt] = (f32x4){0.f, 0.f, 0.f, 0.f};
        for (int kk = 0; kk < 4; ++kk)
            for (int nt = 0; nt < 4; ++nt) {
                f16x8 khf = *(const f16x8*)(&Khs[kk * 2048 + (nt * 16 + lrow) * 32 + quad * 8]);
                sc[0][nt] = __builtin_amdgcn_mfma_f32_16x16x32_f16(khf, qf[0][kk], sc[0][nt], 0, 0, 0);
                sc[1][nt] = __builtin_amdgcn_mfma_f32_16x16x32_f16(khf, qf[1][kk], sc[1][nt], 0, 0, 0);
            }

        f32x4 kbv[4];
        #pragma unroll
        for (int nt = 0; nt < 4; ++nt)
            kbv[nt] = *(const f32x4*)(&kb[nt * 16 + quad * 4]);

        #pragma unroll
        for (int m = 0; m < 2; ++m) {
            float s[4][4];
            float mx = -INFINITY;
            #pragma unroll
            for (int nt = 0; nt < 4; ++nt)
                #pragma unroll
                for (int r = 0; r < 4; ++r) {
                    s[nt][r] = sc[m][nt][r] + kbv[nt][r];
                    mx = fmaxf(mx, s[nt][r]);
                }
            mx = fmaxf(mx, __shfl_xor(mx, 16));
            mx = fmaxf(mx, __shfl_xor(mx, 32));
            float mnew  = fmaxf(mrow[m], mx);
            float alpha = EXP2F(mrow[m] - mnew);
            mrow[m] = mnew;
            float psum = 0.f;
            unsigned pw[8];
            #pragma unroll
            for (int nt = 0; nt < 4; ++nt) {
                float p0 = EXP2F(s[nt][0] - mnew);
                float p1 = EXP2F(s[nt][1] - mnew);
                float p2 = EXP2F(s[nt][2] - mnew);
                float p3 = EXP2F(s[nt][3] - mnew);
                psum += (p0 + p1) + (p2 + p3);
                pw[nt * 2]     = pk2h(p0, p1);
                pw[nt * 2 + 1] = pk2h(p2, p3);
            }
            lsum[m] = lsum[m] * alpha + psum;
            float av0 = __shfl(alpha, quad * 4 + 0);
            float av1 = __shfl(alpha, quad * 4 + 1);
            float av2 = __shfl(alpha, quad * 4 + 2);
            float av3 = __shfl(alpha, quad * 4 + 3);
            #pragma unroll
            for (int dt = 0; dt < 8; ++dt) {
                Ofr[m][dt][0] *= av0;
                Ofr[m][dt][1] *= av1;
                Ofr[m][dt][2] *= av2;
                Ofr[m][dt][3] *= av3;
            }
            int prow = (wave * 32 + m * 16 + lrow) * LV;
            #pragma unroll
            for (int nt = 0; nt < 4; ++nt) {
                uint2 wv; wv.x = pw[nt * 2]; wv.y = pw[nt * 2 + 1];
                *(uint2*)(&Ps[prow + nt * 16 + quad * 4]) = wv;
            }
        }

        for (int c = 0; c < 2; ++c) {
            f16x8 pa0 = *(const f16x8*)(&Ps[(wave * 32 + lrow) * LV + c * 32 + quad * 8]);
            f16x8 pa1 = *(const f16x8*)(&Ps[(wave * 32 + 16 + lrow) * LV + c * 32 + quad * 8]);
            for (int dt = 0; dt < 8; ++dt) {
                f16x8 vb = *(const f16x8*)(&Vts[c * 4096 + (dt * 16 + lrow) * 32 + quad * 8]);
                Ofr[0][dt] = __builtin_amdgcn_mfma_f32_16x16x32_f16(pa0, vb, Ofr[0][dt], 0, 0, 0);
                Ofr[1][dt] = __builtin_amdgcn_mfma_f32_16x16x32_f16(pa1, vb, Ofr[1][dt], 0, 0, 0);
            }
        }
        __syncthreads();
    }

    size_t obase = (size_t)(kz * NHEAD + h) * S_LEN;
    for (int m = 0; m < 2; ++m) {
        float rs = lsum[m];
        rs += __shfl_xor(rs, 16);
        rs += __shfl_xor(rs, 32);
        if (quad == 0) {
            int qrow = q0 + wave * 32 + m * 16 + lrow;
            ML[(obase + qrow) * 2]     = mrow[m];
            ML[(obase + qrow) * 2 + 1] = rs;
        }
        for (int r = 0; r < 4; ++r) {
            int qrow = q0 + wave * 32 + m * 16 + quad * 4 + r;
            unsigned short* op = OP + (obase + qrow) * HD;
            for (int dt = 0; dt < 8; ++dt)
                op[dt * 16 + lrow] = f2h(Ofr[m][dt][r]);
        }
    }
}

// ---------------- merge the two key-halves (log2 domain) -> fp16 Obf -------
__global__ __launch_bounds__(256) void flash_merge(const unsigned short* __restrict__ OP,
                                                   const float* __restrict__ ML,
                                                   unsigned short* __restrict__ Obf) {
    int row = blockIdx.x * 2 + (threadIdx.x >> 7);   // h*2048 + q
    int d   = threadIdx.x & 127;
    int h = row >> 11, q = row & 2047;
    size_t i0 = (size_t)h * S_LEN + q;
    size_t i1 = (size_t)(NHEAD + h) * S_LEN + q;
    float m0 = ML[i0 * 2], l0 = ML[i0 * 2 + 1];
    float m1 = ML[i1 * 2], l1 = ML[i1 * 2 + 1];
    float mf = fmaxf(m0, m1);
    float w0 = EXP2F(m0 - mf), w1 = EXP2F(m1 - mf);
    float inv = 1.f / (l0 * w0 + l1 * w1);
    float o = (h2f(OP[i0 * HD + d]) * w0 + h2f(OP[i1 * HD + d]) * w1) * inv;
    Obf[(size_t)q * HID + h * HD + d] = f2h(o);
}

// ---------------- launch ----------------
extern "C" void kernel_launch(void* const* d_in, const int* in_sizes, int n_in,
                              void* d_out, int out_size, void* d_ws, size_t ws_size,
                              hipStream_t stream) {
    const float* hs   = (const float*)d_in[0];
    const float* cosb = (const float*)d_in[1];
    const float* sinb = (const float*)d_in[2];
    const float* wq   = (const float*)d_in[3];
    const float* wk   = (const float*)d_in[4];
    const float* wv   = (const float*)d_in[5];
    const float* wo   = (const float*)d_in[6];
    float* out = (float*)d_out;
    char*  ws  = (char*)d_ws;

    // shared segments (both paths)
    unsigned short* w_qk16 = (unsigned short*)(ws);                // [0, 33.5M)
    unsigned short* hs16   = (unsigned short*)(ws + 67108864);
    unsigned short* w_v16  = (unsigned short*)(ws + 75497472);
    unsigned short* w_o16  = (unsigned short*)(ws + 83886080);
    unsigned short* Vt     = (unsigned short*)(ws + 92274688);

    static int use256 = -1;
    if (use256 < 0) {
        hipError_t e = hipFuncSetAttribute((const void*)gemm256_qk,
                                           hipFuncAttributeMaxDynamicSharedMemorySize,
                                           131072);
        use256 = (e == hipSuccess) ? 1 : 0;
    }

    // fused casts (5 segments, 28672 blocks)
    cast5<<<28672, 256, 0, stream>>>(hs, wq, wk, wv, wo, hs16, w_qk16, w_v16, w_o16);

    if (use256) {
        // fused-path layout:
        //  [0, 16.8M)       OP   (after gemm256; w_qk16 dead by then)
        //  [16.8M, 17.3M)   ML
        //  [33.5M, 41.9M)   Q16  (written DURING gemm256 epilogue - disjoint from w_qk16/hs16)
        //  [41.9M, 50.3M)   K16
        //  [50.3M, 50.5M)   kbias
        //  [52.4M, 60.8M)   Obf
        unsigned short* OPn  = (unsigned short*)(ws);
        float*          MLn  = (float*)(ws + 16777216);
        unsigned short* Q16n = (unsigned short*)(ws + 33554432);
        unsigned short* K16n = (unsigned short*)(ws + 41943040);
        float*          kbn  = (float*)(ws + 50331648);
        unsigned short* Obfn = (unsigned short*)(ws + 52428800);

        // QK projection + fused softplus/rsqrt/RoPE epilogue (no qk16!)
        gemm256_qk<<<256, 512, 131072, stream>>>(hs16, w_qk16, cosb, sinb,
                                                 Q16n, K16n, kbn);
        // V^T projection [2048_d, 2048_s]
        gemm_nt_f16<true><<<dim3(16, 16), 256, 0, stream>>>(w_v16, hs16, Vt, HID, S_LEN, K_HID);
        // flash attention (key-split 2, XCD-remapped flat grid)
        flash_mfma<<<512, 256, 0, stream>>>(Q16n, K16n, Vt, kbn, OPn, MLn);
        // merge halves -> fp16 attn_out
        flash_merge<<<(NHEAD * S_LEN) / 2, 256, 0, stream>>>(OPn, MLn, Obfn);
        // output projection
        gemm_nt_f16<false><<<dim3(16, 16), 256, 0, stream>>>(Obfn, w_o16, out, S_LEN, HID, K_HID);
    } else {
        // fallback: original R4 flow + layout
        unsigned short* Q16   = (unsigned short*)(ws);
        unsigned short* K16   = (unsigned short*)(ws + 8388608);
        float*          kbias = (float*)(ws + 16777216);
        unsigned short* qk16  = (unsigned short*)(ws + 33554432);
        unsigned short* OP    = (unsigned short*)(ws + 33554432);
        float*          ML    = (float*)(ws + 50331648);
        unsigned short* Obf   = (unsigned short*)(ws + 67108864);   // aliases hs16

        gemm_qkv<<<1280, 256, 0, stream>>>(hs16, w_qk16, w_v16, qk16, Vt);
        prep_qk<<<(NHEAD * S_LEN) / 4, 256, 0, stream>>>(qk16, cosb, sinb,
                                                         Q16, K16, kbias);
        flash_mfma<<<512, 256, 0, stream>>>(Q16, K16, Vt, kbias, OP, ML);
        flash_merge<<<(NHEAD * S_LEN) / 2, 256, 0, stream>>>(OP, ML, Obf);
        gemm_nt_f16<false><<<dim3(16, 16), 256, 0, stream>>>(Obf, w_o16, out, S_LEN, HID, K_HID);
    }
}

// Round 8
// 410.187 us; speedup vs baseline: 1.1773x; 1.1773x over previous
//
#include <hip/hip_runtime.h>
#include <stdint.h>

// ---------------- problem constants ----------------
#define S_LEN 2048
#define HID   2048
#define NHEAD 16
#define HD    128     // head dim
#define NQK   8192    // concat q,k rows of [w_q; w_k]
#define K_HID 2048

typedef _Float16 f16x8 __attribute__((ext_vector_type(8)));
typedef float    f32x4 __attribute__((ext_vector_type(4)));

__device__ __forceinline__ unsigned short f2h(float f) {
    _Float16 h = (_Float16)f;                    // RNE
    union { _Float16 h; unsigned short u; } c; c.h = h;
    return c.u;
}
__device__ __forceinline__ float h2f(unsigned short b) {
    union { unsigned short u; _Float16 h; } c; c.u = b;
    return (float)c.h;
}
__device__ __forceinline__ float softplus_f(float x) {
    return (x > 20.f) ? x : log1pf(expf(x));
}
// 2 f32 -> packed 2xfp16 (RTZ) in one v_cvt_pkrtz
__device__ __forceinline__ unsigned pk2h(float a, float b) {
    auto w = __builtin_amdgcn_cvt_pkrtz(a, b);
    union { decltype(w) h; unsigned u; } c; c.h = w;
    return c.u;
}
#define EXP2F(x) __builtin_amdgcn_exp2f(x)
#define LOG2E 1.44269504088896f
#define LN2F  0.6931471805599453f
// async global->LDS, 16 B/lane; LDS dest = wave-uniform base + lane*16
__device__ __forceinline__ void gload_lds16(const unsigned short* g, unsigned short* l) {
    __builtin_amdgcn_global_load_lds(
        (const __attribute__((address_space(1))) unsigned int*)g,
        (__attribute__((address_space(3))) unsigned int*)l, 16, 0, 0);
}
// raw barrier (no vmcnt drain) + compiler memory fences
__device__ __forceinline__ void bar() {
    asm volatile("" ::: "memory");
    __builtin_amdgcn_s_barrier();
    asm volatile("" ::: "memory");
}
#define VMCNT(n) asm volatile("s_waitcnt vmcnt(" #n ")" ::: "memory")

// ---------------- fused cast fp32 -> fp16, 5 segments ----------------
__global__ __launch_bounds__(256) void cast5(const float* __restrict__ hs,
                                             const float* __restrict__ wq,
                                             const float* __restrict__ wk,
                                             const float* __restrict__ wv,
                                             const float* __restrict__ wo,
                                             unsigned short* __restrict__ hs16,
                                             unsigned short* __restrict__ wqk16,
                                             unsigned short* __restrict__ wv16,
                                             unsigned short* __restrict__ wo16) {
    int b = blockIdx.x;
    const float* src;
    unsigned short* dst;
    int i;
    if (b < 4096)       { src = hs; dst = hs16;                          i = b; }
    else if (b < 12288) { src = wq; dst = wqk16;                         i = b - 4096; }
    else if (b < 20480) { src = wk; dst = wqk16 + (size_t)4096 * K_HID;  i = b - 12288; }
    else if (b < 24576) { src = wv; dst = wv16;                          i = b - 20480; }
    else                { src = wo; dst = wo16;                          i = b - 24576; }
    int idx = i * 256 + threadIdx.x;
    float4 v = ((const float4*)src)[idx];
    ushort4 o;
    o.x = f2h(v.x); o.y = f2h(v.y); o.z = f2h(v.z); o.w = f2h(v.w);
    ((ushort4*)dst)[idx] = o;
}

// ---------------- shared NT-GEMM body (fp16 in, fp16 or fp32 out) ----------
// 128x128 tile, BK=32, 4 waves (2x2), 4x4 MFMA tiles/wave; m97 staging.
template <bool OUT_F16>
__device__ __forceinline__ void gemm_body(const unsigned short* __restrict__ A,
                                          const unsigned short* __restrict__ B,
                                          void* __restrict__ Cv,
                                          int m0, int n0, int N,
                                          unsigned short* As, unsigned short* Bs) {
    const int t    = threadIdx.x;
    const int wave = t >> 6;
    const int lane = t & 63;
    const int wm   = wave >> 1, wn = wave & 1;
    const int lrow = lane & 15, quad = lane >> 4;
    const int srow = lane >> 2;
    const int scol = (lane & 3) * 8;

    f32x4 acc[4][4];
    for (int i = 0; i < 4; ++i)
        for (int j = 0; j < 4; ++j)
            acc[i][j] = (f32x4){0.f, 0.f, 0.f, 0.f};

    for (int k0 = 0; k0 < K_HID; k0 += 32) {
        for (int c = 0; c < 2; ++c) {
            int ch = wave * 2 + c;     // 0..7
            int row = ch * 16 + srow;  // 0..127
            gload_lds16(A + (size_t)(m0 + row) * K_HID + k0 + scol, &As[ch * 512]);
            gload_lds16(B + (size_t)(n0 + row) * K_HID + k0 + scol, &Bs[ch * 512]);
        }
        __syncthreads();

        f16x8 af[4], bfr[4];
        for (int tm = 0; tm < 4; ++tm)
            af[tm]  = *(const f16x8*)(&As[(wm * 64 + tm * 16 + lrow) * 32 + quad * 8]);
        for (int tn = 0; tn < 4; ++tn)
            bfr[tn] = *(const f16x8*)(&Bs[(wn * 64 + tn * 16 + lrow) * 32 + quad * 8]);
        for (int tm = 0; tm < 4; ++tm)
            for (int tn = 0; tn < 4; ++tn)
                acc[tm][tn] = __builtin_amdgcn_mfma_f32_16x16x32_f16(af[tm], bfr[tn], acc[tm][tn], 0, 0, 0);
        __syncthreads();
    }

    for (int tm = 0; tm < 4; ++tm)
        for (int tn = 0; tn < 4; ++tn) {
            int col = n0 + wn * 64 + tn * 16 + lrow;
            for (int r = 0; r < 4; ++r) {
                int row = m0 + wm * 64 + tm * 16 + quad * 4 + r;
                if (OUT_F16)
                    ((unsigned short*)Cv)[(size_t)row * N + col] = f2h(acc[tm][tn][r]);
                else
                    ((float*)Cv)[(size_t)row * N + col] = acc[tm][tn][r];
            }
        }
}

// legacy fused launch (fallback only): QK projection + V^T projection
__global__ __launch_bounds__(256) void gemm_qkv(const unsigned short* __restrict__ hs16,
                                                const unsigned short* __restrict__ wqk16,
                                                const unsigned short* __restrict__ wv16,
                                                unsigned short* __restrict__ qk16,
                                                unsigned short* __restrict__ Vt) {
    __shared__ __align__(16) unsigned short As[128 * 32];
    __shared__ __align__(16) unsigned short Bs[128 * 32];
    int b = blockIdx.x;
    if (b < 1024) {
        gemm_body<true>(hs16, wqk16, qk16, (b >> 6) * 128, (b & 63) * 128, NQK, As, Bs);
    } else {
        b -= 1024;
        gemm_body<true>(wv16, hs16, Vt, (b >> 4) * 128, (b & 15) * 128, S_LEN, As, Bs);
    }
}

// plain single GEMM (128^2 tile; used for V^T and O-projection)
template <bool OUT_F16>
__global__ __launch_bounds__(256) void gemm_nt_f16(const unsigned short* __restrict__ A,
                                                   const unsigned short* __restrict__ B,
                                                   void* __restrict__ Cv,
                                                   int M, int N, int Kd) {
    __shared__ __align__(16) unsigned short As[128 * 32];
    __shared__ __align__(16) unsigned short Bs[128 * 32];
    gemm_body<OUT_F16>(A, B, Cv, blockIdx.y * 128, blockIdx.x * 128, N, As, Bs);
}

// ---------------- 256x256 cross-phase GEMM + FUSED prep epilogue -----------
// Main loop unchanged (zigzag quadrant walk, counted vmcnt, 4 bars/tile).
// R7 POST-MORTEM FIX: E3 previously indexed acc[mlo+mi] with mlo = runtime
// (wn==0 ? 0 : 4). ONE runtime index forces the ENTIRE acc[8][4] (512 B) into
// scratch for the kernel's whole lifetime (rule: compiler can't prove element)
// -> every main-loop MFMA round-tripped private memory = ~550 MB HBM writes,
// MfmaUtil 14%, launch-bounds-invariant. Fix: two explicit branches with
// LITERAL loop bounds so every acc index is compile-time.
__global__ __launch_bounds__(512, 1) void gemm256_qk(const unsigned short* __restrict__ A,
                                                     const unsigned short* __restrict__ B,
                                                     const float* __restrict__ cosb,
                                                     const float* __restrict__ sinb,
                                                     unsigned short* __restrict__ Qo,
                                                     unsigned short* __restrict__ Ko,
                                                     float* __restrict__ kb_out) {
    extern __shared__ __align__(16) unsigned short lds[];   // 65536 halves
    __shared__ float sred[3][256];                           // lg2 x2, ksq
    const int t    = threadIdx.x;
    const int wave = t >> 6;
    const int lane = t & 63;
    const int wm   = wave >> 2, wn = wave & 3;     // 2 x 4 wave grid
    const int lrow = lane & 15, quad = lane >> 4;

    const int x  = blockIdx.x & 7;
    const int sl = blockIdx.x >> 3;                // 0..31
    const int tm = ((x >> 2) << 2) + (sl >> 3);    // 0..7
    const int tn = ((x & 3) << 3) + (sl & 7);      // 0..31
    const int m0 = tm << 8, n0 = tn << 8;

    const int srow = lane >> 2;                               // row in subtile
    const int scol = ((lane & 3) * 8) ^ ((lane >> 5) << 4);   // halves
    const unsigned short* Ag = A + (size_t)(m0 + wave * 16 + srow) * K_HID + scol;
    const unsigned short* Bg = B + (size_t)(n0 + wave * 16 + srow) * K_HID + scol;

    const int swz = (lrow * 32 + quad * 8) ^ ((lrow >> 3) << 4);

    f32x4 acc[8][4];
    #pragma unroll
    for (int i = 0; i < 8; ++i)
        #pragma unroll
        for (int j = 0; j < 4; ++j) acc[i][j] = (f32x4){0.f, 0.f, 0.f, 0.f};

    {
        unsigned short* la = lds + wave * 1024;
        gload_lds16(Ag,               la);
        gload_lds16(Ag + 32,          la + 512);
        gload_lds16(Ag + 262144,      la + 8192);
        gload_lds16(Ag + 262144 + 32, la + 8704);
        unsigned short* lb = la + 16384;
        gload_lds16(Bg,               lb);
        gload_lds16(Bg + 32,          lb + 512);
        gload_lds16(Bg + 262144,      lb + 8192);
        gload_lds16(Bg + 262144 + 32, lb + 8704);
    }
    VMCNT(0);
    bar();   // tile 0 published

    f16x8 ah[4][2], b01[2][2];

    const int NT = K_HID / 64;   // 32
    #pragma unroll 1
    for (int t2 = 0; t2 < NT; ++t2) {
        const int buf = t2 & 1;
        const unsigned short* Lb = lds + buf * 32768;
        unsigned short*       Ln = lds + (buf ^ 1) * 32768 + wave * 1024;
        const int k1  = (t2 + 1) * 64;
        const bool pre = (t2 < NT - 1);

        f16x8 al[4][2], b23[2][2];

        // ---- S0: stage A(t+1) | read al(t) | MFMA Q(1,0) of t-1 | read b01(t) ----
        if (pre) {
            gload_lds16(Ag + k1,               Ln);
            gload_lds16(Ag + k1 + 32,          Ln + 512);
            gload_lds16(Ag + 262144 + k1,      Ln + 8192);
            gload_lds16(Ag + 262144 + k1 + 32, Ln + 8704);
        }
        #pragma unroll
        for (int i = 0; i < 4; ++i) {
            al[i][0] = *(const f16x8*)(Lb + (wm * 8 + i) * 1024 + swz);
            al[i][1] = *(const f16x8*)(Lb + (wm * 8 + i) * 1024 + 512 + swz);
        }
        if (t2) {
            __builtin_amdgcn_s_setprio(1);
            #pragma unroll
            for (int i = 0; i < 4; ++i)
                #pragma unroll
                for (int j = 0; j < 2; ++j) {
                    acc[4 + i][j] = __builtin_amdgcn_mfma_f32_16x16x32_f16(ah[i][0], b01[j][0], acc[4 + i][j], 0, 0, 0);
                    acc[4 + i][j] = __builtin_amdgcn_mfma_f32_16x16x32_f16(ah[i][1], b01[j][1], acc[4 + i][j], 0, 0, 0);
                }
            __builtin_amdgcn_s_setprio(0);
        }
        #pragma unroll
        for (int j = 0; j < 2; ++j) {
            b01[j][0] = *(const f16x8*)(Lb + 16384 + (wn * 4 + j) * 1024 + swz);
            b01[j][1] = *(const f16x8*)(Lb + 16384 + (wn * 4 + j) * 1024 + 512 + swz);
        }
        bar();

        // ---- S1: stage B(t+1) | read b23(t) || MFMA Q(0,0) = al*b01 ----
        if (pre) {
            gload_lds16(Bg + k1,               Ln + 16384);
            gload_lds16(Bg + k1 + 32,          Ln + 16896);
            gload_lds16(Bg + 262144 + k1,      Ln + 24576);
            gload_lds16(Bg + 262144 + k1 + 32, Ln + 25088);
        }
        #pragma unroll
        for (int j = 0; j < 2; ++j) {
            b23[j][0] = *(const f16x8*)(Lb + 16384 + (wn * 4 + 2 + j) * 1024 + swz);
            b23[j][1] = *(const f16x8*)(Lb + 16384 + (wn * 4 + 2 + j) * 1024 + 512 + swz);
        }
        __builtin_amdgcn_s_setprio(1);
        #pragma unroll
        for (int i = 0; i < 4; ++i)
            #pragma unroll
            for (int j = 0; j < 2; ++j) {
                acc[i][j] = __builtin_amdgcn_mfma_f32_16x16x32_f16(al[i][0], b01[j][0], acc[i][j], 0, 0, 0);
                acc[i][j] = __builtin_amdgcn_mfma_f32_16x16x32_f16(al[i][1], b01[j][1], acc[i][j], 0, 0, 0);
            }
        __builtin_amdgcn_s_setprio(0);
        bar();

        // ---- S2: read ah(t) || MFMA Q(0,1) = al*b23 ----
        #pragma unroll
        for (int i = 0; i < 4; ++i) {
            ah[i][0] = *(const f16x8*)(Lb + (wm * 8 + 4 + i) * 1024 + swz);
            ah[i][1] = *(const f16x8*)(Lb + (wm * 8 + 4 + i) * 1024 + 512 + swz);
        }
        __builtin_amdgcn_s_setprio(1);
        #pragma unroll
        for (int i = 0; i < 4; ++i)
            #pragma unroll
            for (int j = 0; j < 2; ++j) {
                acc[i][2 + j] = __builtin_amdgcn_mfma_f32_16x16x32_f16(al[i][0], b23[j][0], acc[i][2 + j], 0, 0, 0);
                acc[i][2 + j] = __builtin_amdgcn_mfma_f32_16x16x32_f16(al[i][1], b23[j][1], acc[i][2 + j], 0, 0, 0);
            }
        __builtin_amdgcn_s_setprio(0);
        bar();

        // ---- S3: MFMA Q(1,1) = ah*b23 ; publish tile t+1 ----
        __builtin_amdgcn_s_setprio(1);
        #pragma unroll
        for (int i = 0; i < 4; ++i)
            #pragma unroll
            for (int j = 0; j < 2; ++j) {
                acc[4 + i][2 + j] = __builtin_amdgcn_mfma_f32_16x16x32_f16(ah[i][0], b23[j][0], acc[4 + i][2 + j], 0, 0, 0);
                acc[4 + i][2 + j] = __builtin_amdgcn_mfma_f32_16x16x32_f16(ah[i][1], b23[j][1], acc[4 + i][2 + j], 0, 0, 0);
            }
        __builtin_amdgcn_s_setprio(0);
        VMCNT(0);
        bar();
    }

    // deferred final quadrant Q(1,0) of the last tile
    __builtin_amdgcn_s_setprio(1);
    #pragma unroll
    for (int i = 0; i < 4; ++i)
        #pragma unroll
        for (int j = 0; j < 2; ++j) {
            acc[4 + i][j] = __builtin_amdgcn_mfma_f32_16x16x32_f16(ah[i][0], b01[j][0], acc[4 + i][j], 0, 0, 0);
            acc[4 + i][j] = __builtin_amdgcn_mfma_f32_16x16x32_f16(ah[i][1], b01[j][1], acc[4 + i][j], 0, 0, 0);
        }
    __builtin_amdgcn_s_setprio(0);
    bar();   // every wave's LDS reads consumed -> LDS free for epilogue reuse

    // ================= fused prep epilogue =================
    const int  headq = tn & 15;
    const bool isK   = (tn >= 16);
    float* Lf = (float*)lds;                  // 256 x 128 f32 exchange
    unsigned short* Ls = lds;                 // ushort view (fp16 staging)
    const int swl = (quad & 1) << 4;          // == ((row>>2)&1)<<4 for this lane's rows

    // E1: sigma waves (wn>=2): inv = rsqrt(softplus+eps) -> Lf; lg2 row partials
    if (wn >= 2) {
        #pragma unroll
        for (int m = 0; m < 8; ++m)
            #pragma unroll
            for (int r = 0; r < 4; ++r) {
                const int row = wm * 128 + m * 16 + quad * 4 + r;
                float lgs = 0.f;
                #pragma unroll
                for (int n = 0; n < 4; ++n) {
                    const int d = (wn - 2) * 64 + n * 16 + lrow;
                    float xv = acc[m][n][r];
                    float sp = (xv > 20.f) ? xv
                             : LN2F * __log2f(1.f + EXP2F(xv * LOG2E));
                    float sg = sp + 1e-4f;
                    Lf[row * 128 + (d ^ swl)] = rsqrtf(sg);
                    if (isK) lgs += __log2f(sg);
                }
                if (isK) {
                    lgs += __shfl_xor(lgs, 1); lgs += __shfl_xor(lgs, 2);
                    lgs += __shfl_xor(lgs, 4); lgs += __shfl_xor(lgs, 8);
                    if (lrow == 0) sred[wn - 2][row] = lgs;
                }
            }
    }
    bar();   // inv published

    // E2: mu waves: w = acc*inv in-place; publish the half the partner needs
    if (wn < 2) {
        #pragma unroll
        for (int m = 0; m < 8; ++m)
            #pragma unroll
            for (int n = 0; n < 4; ++n) {
                const int d = wn * 64 + n * 16 + lrow;
                #pragma unroll
                for (int r = 0; r < 4; ++r) {
                    const int row = wm * 128 + m * 16 + quad * 4 + r;
                    float w = acc[m][n][r] * Lf[row * 128 + (d ^ swl)];
                    acc[m][n][r] = w;
                    const bool keep = (wn == 0) ? (m < 4) : (m >= 4);
                    if (!keep) Lf[row * 128 + (d ^ swl)] = w;   // own slot, 1:1
                }
            }
    }
    bar();   // cross-half w published; "keep" slots (stale inv) now DEAD

    // E3: RoPE pairs -> fp16 staged into the dead checkerboard of Lf.
    // Dead slots: rows rr<64 at d<64 (fb=0), rows rr>=64 at d>=64 (fb=64).
    // TWO LITERAL-BOUND BRANCHES: every acc[m][..] index compile-time (no scratch).
#define E3_ROW(MM, WLO_STMT)                                                    \
            _Pragma("unroll")                                                   \
            for (int r = 0; r < 4; ++r) {                                       \
                const int row = wm * 128 + (MM) * 16 + quad * 4 + r;            \
                const int rr  = row & 127;                                      \
                const int fb  = (rr < 64) ? 0 : 64;                             \
                const int s   = m0 + row;                                       \
                unsigned short* st = Ls + (row * 128 + fb) * 2;                 \
                float kq = 0.f;                                                 \
                _Pragma("unroll")                                               \
                for (int n = 0; n < 4; ++n) {                                   \
                    const int dl = n * 16 + lrow;                               \
                    float c  = cosb[(size_t)s * HD + dl];                       \
                    float sn = sinb[(size_t)s * HD + dl];                       \
                    float wlo, whi;                                             \
                    WLO_STMT;                                                   \
                    float olo = wlo * c - whi * sn;                             \
                    float ohi = whi * c + wlo * sn;                             \
                    if (!isK) {                                                 \
                        st[dl]      = f2h(olo * LOG2E);                         \
                        st[dl + 64] = f2h(ohi * LOG2E);                         \
                    } else {                                                    \
                        unsigned short klo = f2h(olo), khi = f2h(ohi);          \
                        st[dl]      = klo;                                      \
                        st[dl + 64] = khi;                                      \
                        float a = h2f(klo), b2 = h2f(khi);                      \
                        kq += a * a + b2 * b2;                                  \
                    }                                                           \
                }                                                               \
                if (isK) {                                                      \
                    kq += __shfl_xor(kq, 1); kq += __shfl_xor(kq, 2);           \
                    kq += __shfl_xor(kq, 4); kq += __shfl_xor(kq, 8);           \
                    if (lrow == 0) sred[2][row] = kq;                           \
                }                                                               \
            }

    if (wn == 0) {          // owns m = 0..3 (low rows); acc holds w_lo
        #pragma unroll
        for (int mi = 0; mi < 4; ++mi) {
            E3_ROW(mi,
                   wlo = acc[mi][n][r];
                   whi = Lf[row * 128 + ((dl + 64) ^ swl)])
        }
    } else if (wn == 1) {   // owns m = 4..7 (high rows); acc holds w_hi
        #pragma unroll
        for (int mi = 0; mi < 4; ++mi) {
            E3_ROW(4 + mi,
                   whi = acc[4 + mi][n][r];
                   wlo = Lf[row * 128 + (dl ^ swl)])
        }
    }
#undef E3_ROW
    bar();   // staging + sred complete

    // copy-out: block output = contiguous 64 KB; uint4 per lane, wave-contiguous
    {
        unsigned short* Go = (isK ? Ko : Qo) + ((size_t)headq * S_LEN + m0) * HD;
        #pragma unroll
        for (int pass = 0; pass < 8; ++pass) {
            int idx = pass * 4096 + t * 8;       // halves
            int row = idx >> 7;
            int d   = idx & 127;
            int rr  = row & 127;
            int fb  = (rr < 64) ? 0 : 64;
            uint4 v = *(const uint4*)(Ls + (row * 128 + fb) * 2 + d);
            *(uint4*)(Go + idx) = v;
        }
        if (isK && t < 256) {
            const int row = t;
            kb_out[(size_t)headq * S_LEN + m0 + row] =
                -0.5f * (LOG2E * sred[2][row] + sred[0][row] + sred[1][row]);
        }
    }
}

// ---------------- prep (FALLBACK PATH ONLY) --------------------------------
__global__ __launch_bounds__(256) void prep_qk(const unsigned short* __restrict__ qk,
                                               const float* __restrict__ cosb,
                                               const float* __restrict__ sinb,
                                               unsigned short* __restrict__ Q16,
                                               unsigned short* __restrict__ K16,
                                               float* __restrict__ kbias) {
    int gid  = blockIdx.x * 4 + (threadIdx.x >> 6);
    int lane = threadIdx.x & 63;
    int h = gid >> 11;
    int s = gid & 2047;
    int d1 = lane, d2 = lane + 64;
    const unsigned short* row = qk + (size_t)s * NQK;
    float c1 = cosb[s * HD + d1], c2 = cosb[s * HD + d2];
    float s1 = sinb[s * HD + d1], s2 = sinb[s * HD + d2];
    size_t ob = ((size_t)h * S_LEN + s) * HD;

    {   // Q side (scaled by log2e)
        int base = h * 256;
        float mu1 = h2f(row[base + d1]),       mu2 = h2f(row[base + d2]);
        float sg1 = softplus_f(h2f(row[base + 128 + d1])) + 1e-4f;
        float sg2 = softplus_f(h2f(row[base + 128 + d2])) + 1e-4f;
        float w1 = mu1 * rsqrtf(sg1), w2 = mu2 * rsqrtf(sg2);
        float o1 = w1 * c1 - w2 * s1;
        float o2 = w2 * c2 + w1 * s2;
        Q16[ob + d1] = f2h(o1 * LOG2E);
        Q16[ob + d2] = f2h(o2 * LOG2E);
    }
    {   // K side + bias from ROUNDED k̂
        int base = 4096 + h * 256;
        float mu1 = h2f(row[base + d1]),       mu2 = h2f(row[base + d2]);
        float sg1 = softplus_f(h2f(row[base + 128 + d1])) + 1e-4f;
        float sg2 = softplus_f(h2f(row[base + 128 + d2])) + 1e-4f;
        float w1 = mu1 * rsqrtf(sg1), w2 = mu2 * rsqrtf(sg2);
        float o1 = w1 * c1 - w2 * s1;
        float o2 = w2 * c2 + w1 * s2;
        unsigned short k1 = f2h(o1), k2 = f2h(o2);
        K16[ob + d1] = k1; K16[ob + d2] = k2;
        float r1 = h2f(k1), r2 = h2f(k2);
        float part = r1 * r1 + r2 * r2 + logf(sg1) + logf(sg2);
        for (int off = 32; off > 0; off >>= 1) part += __shfl_down(part, off);
        if (lane == 0) kbias[(size_t)h * S_LEN + s] = -0.5f * LOG2E * part;
    }
}

// ---------------- flash attention, fp16 MFMA, key-split partials -----------
// (unchanged from R4: swapped QK^T, exp2 domain, XCD-remapped flat grid)
__global__ __launch_bounds__(256, 2) void flash_mfma(const unsigned short* __restrict__ Q16,
                                                     const unsigned short* __restrict__ K16,
                                                     const unsigned short* __restrict__ Vt,
                                                     const float* __restrict__ kbias,
                                                     unsigned short* __restrict__ OP,
                                                     float* __restrict__ ML) {
    constexpr int LV = 72;   // P row pad
    __shared__ __align__(16) unsigned short Khs[4 * 64 * 32];    // 16 KB
    __shared__ __align__(16) unsigned short Vts[2 * 128 * 32];   // 16 KB
    __shared__ __align__(16) unsigned short Ps[128 * LV];        // 18.4 KB
    __shared__ float kb[64];

    const int t    = threadIdx.x;
    const int bb   = blockIdx.x;
    const int cc   = (bb & 7) | (((bb >> 7) & 3) << 3);   // combo 0..31
    const int h    = cc & 15;
    const int kz   = cc >> 4;
    const int q0   = ((bb >> 3) & 15) * 128;
    const int wave = t >> 6;
    const int lane = t & 63;
    const int lrow = lane & 15, quad = lane >> 4;
    const int srow = lane >> 2;
    const int scol = (lane & 3) * 8;

    f16x8 qf[2][4];
    for (int m = 0; m < 2; ++m) {
        size_t rb = ((size_t)h * S_LEN + q0 + wave * 32 + m * 16 + lrow) * HD;
        for (int kk = 0; kk < 4; ++kk)
            qf[m][kk] = *(const f16x8*)(Q16 + rb + kk * 32 + quad * 8);
    }

    float mrow[2], lsum[2];
    f32x4 Ofr[2][8];
    for (int m = 0; m < 2; ++m) { mrow[m] = -INFINITY; lsum[m] = 0.f; }
    for (int m = 0; m < 2; ++m)
        for (int d = 0; d < 8; ++d) Ofr[m][d] = (f32x4){0.f, 0.f, 0.f, 0.f};

    const int kbeg = kz * 1024;
    for (int k0 = kbeg; k0 < kbeg + 1024; k0 += 64) {
        {
            const unsigned short* kgb = K16 + ((size_t)h * S_LEN + k0) * HD;
            const unsigned short* vgb = Vt + ((size_t)h * HD) * S_LEN + k0;
            for (int c = 0; c < 4; ++c) {
                int ch = wave * 4 + c;                 // 0..15
                int kk = ch >> 2;
                int r  = (ch & 3) * 16 + srow;
                gload_lds16(kgb + (size_t)r * HD + kk * 32 + scol, &Khs[ch * 512]);
                int kc = ch >> 3;
                int r2 = (ch & 7) * 16 + srow;
                gload_lds16(vgb + (size_t)r2 * S_LEN + kc * 32 + scol, &Vts[ch * 512]);
            }
            if (t < 64) kb[t] = kbias[(size_t)h * S_LEN + k0 + t];
        }
        __syncthreads();

        f32x4 sc[2][4];
        for (int m = 0; m < 2; ++m)
            for (int nt = 0; nt < 4; ++nt) sc[m][nt] = (f32x4){0.f, 0.f, 0.f, 0.f};
        for (int kk = 0; kk < 4; ++kk)
            for (int nt = 0; nt < 4; ++nt) {
                f16x8 khf = *(const f16x8*)(&Khs[kk * 2048 + (nt * 16 + lrow) * 32 + quad * 8]);
                sc[0][nt] = __builtin_amdgcn_mfma_f32_16x16x32_f16(khf, qf[0][kk], sc[0][nt], 0, 0, 0);
                sc[1][nt] = __builtin_amdgcn_mfma_f32_16x16x32_f16(khf, qf[1][kk], sc[1][nt], 0, 0, 0);
            }

        f32x4 kbv[4];
        #pragma unroll
        for (int nt = 0; nt < 4; ++nt)
            kbv[nt] = *(const f32x4*)(&kb[nt * 16 + quad * 4]);

        #pragma unroll
        for (int m = 0; m < 2; ++m) {
            float s[4][4];
            float mx = -INFINITY;
            #pragma unroll
            for (int nt = 0; nt < 4; ++nt)
                #pragma unroll
                for (int r = 0; r < 4; ++r) {
                    s[nt][r] = sc[m][nt][r] + kbv[nt][r];
                    mx = fmaxf(mx, s[nt][r]);
                }
            mx = fmaxf(mx, __shfl_xor(mx, 16));
            mx = fmaxf(mx, __shfl_xor(mx, 32));
            float mnew  = fmaxf(mrow[m], mx);
            float alpha = EXP2F(mrow[m] - mnew);
            mrow[m] = mnew;
            float psum = 0.f;
            unsigned pw[8];
            #pragma unroll
            for (int nt = 0; nt < 4; ++nt) {
                float p0 = EXP2F(s[nt][0] - mnew);
                float p1 = EXP2F(s[nt][1] - mnew);
                float p2 = EXP2F(s[nt][2] - mnew);
                float p3 = EXP2F(s[nt][3] - mnew);
                psum += (p0 + p1) + (p2 + p3);
                pw[nt * 2]     = pk2h(p0, p1);
                pw[nt * 2 + 1] = pk2h(p2, p3);
            }
            lsum[m] = lsum[m] * alpha + psum;
            float av0 = __shfl(alpha, quad * 4 + 0);
            float av1 = __shfl(alpha, quad * 4 + 1);
            float av2 = __shfl(alpha, quad * 4 + 2);
            float av3 = __shfl(alpha, quad * 4 + 3);
            #pragma unroll
            for (int dt = 0; dt < 8; ++dt) {
                Ofr[m][dt][0] *= av0;
                Ofr[m][dt][1] *= av1;
                Ofr[m][dt][2] *= av2;
                Ofr[m][dt][3] *= av3;
            }
            int prow = (wave * 32 + m * 16 + lrow) * LV;
            #pragma unroll
            for (int nt = 0; nt < 4; ++nt) {
                uint2 wv; wv.x = pw[nt * 2]; wv.y = pw[nt * 2 + 1];
                *(uint2*)(&Ps[prow + nt * 16 + quad * 4]) = wv;
            }
        }

        for (int c = 0; c < 2; ++c) {
            f16x8 pa0 = *(const f16x8*)(&Ps[(wave * 32 + lrow) * LV + c * 32 + quad * 8]);
            f16x8 pa1 = *(const f16x8*)(&Ps[(wave * 32 + 16 + lrow) * LV + c * 32 + quad * 8]);
            for (int dt = 0; dt < 8; ++dt) {
                f16x8 vb = *(const f16x8*)(&Vts[c * 4096 + (dt * 16 + lrow) * 32 + quad * 8]);
                Ofr[0][dt] = __builtin_amdgcn_mfma_f32_16x16x32_f16(pa0, vb, Ofr[0][dt], 0, 0, 0);
                Ofr[1][dt] = __builtin_amdgcn_mfma_f32_16x16x32_f16(pa1, vb, Ofr[1][dt], 0, 0, 0);
            }
        }
        __syncthreads();
    }

    size_t obase = (size_t)(kz * NHEAD + h) * S_LEN;
    for (int m = 0; m < 2; ++m) {
        float rs = lsum[m];
        rs += __shfl_xor(rs, 16);
        rs += __shfl_xor(rs, 32);
        if (quad == 0) {
            int qrow = q0 + wave * 32 + m * 16 + lrow;
            ML[(obase + qrow) * 2]     = mrow[m];
            ML[(obase + qrow) * 2 + 1] = rs;
        }
        for (int r = 0; r < 4; ++r) {
            int qrow = q0 + wave * 32 + m * 16 + quad * 4 + r;
            unsigned short* op = OP + (obase + qrow) * HD;
            for (int dt = 0; dt < 8; ++dt)
                op[dt * 16 + lrow] = f2h(Ofr[m][dt][r]);
        }
    }
}

// ---------------- merge the two key-halves (log2 domain) -> fp16 Obf -------
__global__ __launch_bounds__(256) void flash_merge(const unsigned short* __restrict__ OP,
                                                   const float* __restrict__ ML,
                                                   unsigned short* __restrict__ Obf) {
    int row = blockIdx.x * 2 + (threadIdx.x >> 7);   // h*2048 + q
    int d   = threadIdx.x & 127;
    int h = row >> 11, q = row & 2047;
    size_t i0 = (size_t)h * S_LEN + q;
    size_t i1 = (size_t)(NHEAD + h) * S_LEN + q;
    float m0 = ML[i0 * 2], l0 = ML[i0 * 2 + 1];
    float m1 = ML[i1 * 2], l1 = ML[i1 * 2 + 1];
    float mf = fmaxf(m0, m1);
    float w0 = EXP2F(m0 - mf), w1 = EXP2F(m1 - mf);
    float inv = 1.f / (l0 * w0 + l1 * w1);
    float o = (h2f(OP[i0 * HD + d]) * w0 + h2f(OP[i1 * HD + d]) * w1) * inv;
    Obf[(size_t)q * HID + h * HD + d] = f2h(o);
}

// ---------------- launch ----------------
extern "C" void kernel_launch(void* const* d_in, const int* in_sizes, int n_in,
                              void* d_out, int out_size, void* d_ws, size_t ws_size,
                              hipStream_t stream) {
    const float* hs   = (const float*)d_in[0];
    const float* cosb = (const float*)d_in[1];
    const float* sinb = (const float*)d_in[2];
    const float* wq   = (const float*)d_in[3];
    const float* wk   = (const float*)d_in[4];
    const float* wv   = (const float*)d_in[5];
    const float* wo   = (const float*)d_in[6];
    float* out = (float*)d_out;
    char*  ws  = (char*)d_ws;

    // shared segments (both paths)
    unsigned short* w_qk16 = (unsigned short*)(ws);                // [0, 33.5M)
    unsigned short* hs16   = (unsigned short*)(ws + 67108864);
    unsigned short* w_v16  = (unsigned short*)(ws + 75497472);
    unsigned short* w_o16  = (unsigned short*)(ws + 83886080);
    unsigned short* Vt     = (unsigned short*)(ws + 92274688);

    static int use256 = -1;
    if (use256 < 0) {
        hipError_t e = hipFuncSetAttribute((const void*)gemm256_qk,
                                           hipFuncAttributeMaxDynamicSharedMemorySize,
                                           131072);
        use256 = (e == hipSuccess) ? 1 : 0;
    }

    // fused casts (5 segments, 28672 blocks)
    cast5<<<28672, 256, 0, stream>>>(hs, wq, wk, wv, wo, hs16, w_qk16, w_v16, w_o16);

    if (use256) {
        // fused-path layout:
        //  [0, 16.8M)       OP   (after gemm256; w_qk16 dead by then)
        //  [16.8M, 17.3M)   ML
        //  [33.5M, 41.9M)   Q16  (written DURING gemm256 epilogue - disjoint from w_qk16/hs16)
        //  [41.9M, 50.3M)   K16
        //  [50.3M, 50.5M)   kbias
        //  [52.4M, 60.8M)   Obf
        unsigned short* OPn  = (unsigned short*)(ws);
        float*          MLn  = (float*)(ws + 16777216);
        unsigned short* Q16n = (unsigned short*)(ws + 33554432);
        unsigned short* K16n = (unsigned short*)(ws + 41943040);
        float*          kbn  = (float*)(ws + 50331648);
        unsigned short* Obfn = (unsigned short*)(ws + 52428800);

        // QK projection + fused softplus/rsqrt/RoPE epilogue (no qk16!)
        gemm256_qk<<<256, 512, 131072, stream>>>(hs16, w_qk16, cosb, sinb,
                                                 Q16n, K16n, kbn);
        // V^T projection [2048_d, 2048_s]
        gemm_nt_f16<true><<<dim3(16, 16), 256, 0, stream>>>(w_v16, hs16, Vt, HID, S_LEN, K_HID);
        // flash attention (key-split 2, XCD-remapped flat grid)
        flash_mfma<<<512, 256, 0, stream>>>(Q16n, K16n, Vt, kbn, OPn, MLn);
        // merge halves -> fp16 attn_out
        flash_merge<<<(NHEAD * S_LEN) / 2, 256, 0, stream>>>(OPn, MLn, Obfn);
        // output projection
        gemm_nt_f16<false><<<dim3(16, 16), 256, 0, stream>>>(Obfn, w_o16, out, S_LEN, HID, K_HID);
    } else {
        // fallback: original R4 flow + layout
        unsigned short* Q16   = (unsigned short*)(ws);
        unsigned short* K16   = (unsigned short*)(ws + 8388608);
        float*          kbias = (float*)(ws + 16777216);
        unsigned short* qk16  = (unsigned short*)(ws + 33554432);
        unsigned short* OP    = (unsigned short*)(ws + 33554432);
        float*          ML    = (float*)(ws + 50331648);
        unsigned short* Obf   = (unsigned short*)(ws + 67108864);   // aliases hs16

        gemm_qkv<<<1280, 256, 0, stream>>>(hs16, w_qk16, w_v16, qk16, Vt);
        prep_qk<<<(NHEAD * S_LEN) / 4, 256, 0, stream>>>(qk16, cosb, sinb,
                                                         Q16, K16, kbias);
        flash_mfma<<<512, 256, 0, stream>>>(Q16, K16, Vt, kbias, OP, ML);
        flash_merge<<<(NHEAD * S_LEN) / 2, 256, 0, stream>>>(OP, ML, Obf);
        gemm_nt_f16<false><<<dim3(16, 16), 256, 0, stream>>>(Obf, w_o16, out, S_LEN, HID, K_HID);
    }
}